// Round 1
// baseline (217.311 us; speedup 1.0000x reference)
//
#include <hip/hip_runtime.h>
#include <hip/hip_bf16.h>

// Shapes are fixed by the problem definition.
#define B_   16
#define T_   4096
#define N_   512
#define D_   512
#define EPSF 1e-8f

// GEMM tile params
#define BM 128
#define BN 128
#define BK 64

typedef __attribute__((ext_vector_type(8))) short bf16x8; // 8 bf16 = 4 VGPRs
typedef __attribute__((ext_vector_type(4))) float f32x4;

// round-to-nearest-even f32 -> bf16, packed pair into one u32
__device__ __forceinline__ unsigned int pack2bf(float a, float b) {
  unsigned int ua = __float_as_uint(a);
  ua += 0x7fffu + ((ua >> 16) & 1u);
  unsigned int ub = __float_as_uint(b);
  ub += 0x7fffu + ((ub >> 16) & 1u);
  return (ua >> 16) | (ub & 0xffff0000u);
}

// ---------------------------------------------------------------------------
// Kernel A1: one wave per (b,t) row. Computes ||c||, ||y_t||, dot(c,y_t).
// Writes inv_nc[b*T+t] = 1/max(||c||,eps)  and  r_t[b*T+t] = dot/(n_t*n_c).
// ---------------------------------------------------------------------------
__global__ void rownorms_ct(const float* __restrict__ c,
                            const float* __restrict__ yt,
                            float* __restrict__ inv_nc,
                            float* __restrict__ rt) {
  const int wave = blockIdx.x * (blockDim.x >> 6) + (threadIdx.x >> 6);
  const int lane = threadIdx.x & 63;
  if (wave >= B_ * T_) return;
  const float4* cp = (const float4*)(c + (size_t)wave * D_);
  const float4* tp = (const float4*)(yt + (size_t)wave * D_);
  float cc = 0.f, tt = 0.f, ct = 0.f;
#pragma unroll
  for (int i = 0; i < D_ / 4 / 64; ++i) {  // 2 iters
    float4 a = cp[lane + 64 * i];
    float4 b = tp[lane + 64 * i];
    cc += a.x * a.x + a.y * a.y + a.z * a.z + a.w * a.w;
    tt += b.x * b.x + b.y * b.y + b.z * b.z + b.w * b.w;
    ct += a.x * b.x + a.y * b.y + a.z * b.z + a.w * b.w;
  }
#pragma unroll
  for (int m = 32; m; m >>= 1) {
    cc += __shfl_xor(cc, m);
    tt += __shfl_xor(tt, m);
    ct += __shfl_xor(ct, m);
  }
  if (lane == 0) {
    float nc = fmaxf(sqrtf(cc), EPSF);
    float nt = fmaxf(sqrtf(tt), EPSF);
    inv_nc[wave] = 1.f / nc;
    rt[wave] = ct / (nt * nc);
  }
}

// ---------------------------------------------------------------------------
// Kernel A2: one wave per (b,n) distractor row -> inv_nd.
// ---------------------------------------------------------------------------
__global__ void rownorms_d(const float* __restrict__ yd,
                           float* __restrict__ inv_nd) {
  const int wave = blockIdx.x * (blockDim.x >> 6) + (threadIdx.x >> 6);
  const int lane = threadIdx.x & 63;
  if (wave >= B_ * N_) return;
  const float4* dp = (const float4*)(yd + (size_t)wave * D_);
  float dd = 0.f;
#pragma unroll
  for (int i = 0; i < D_ / 4 / 64; ++i) {
    float4 a = dp[lane + 64 * i];
    dd += a.x * a.x + a.y * a.y + a.z * a.z + a.w * a.w;
  }
#pragma unroll
  for (int m = 32; m; m >>= 1) dd += __shfl_xor(dd, m);
  if (lane == 0) inv_nd[wave] = 1.f / fmaxf(sqrtf(dd), EPSF);
}

// ---------------------------------------------------------------------------
// Kernel B: per batch, C[t,n] = c[t,:]·yd[n,:] via bf16 MFMA (16x16x32),
// epilogue: S[b,t] += sum_n exp(C * inv_nc[t] * inv_nd[n]).
// Tiles: 128x128, BK=64, 4 waves (2x2), each wave 64x64 (4x4 16x16 frags).
// f32 inputs converted to bf16 (RNE) during reg-staged LDS writes.
// LDS rows are 128 B -> XOR-swizzle chunk ^= (row&7) for conflict-free
// ds_read_b128 (guide G4).
// ---------------------------------------------------------------------------
__launch_bounds__(256, 2)
__global__ void gemm_exp_rowsum(const float* __restrict__ c,
                                const float* __restrict__ yd,
                                const float* __restrict__ inv_nc,
                                const float* __restrict__ inv_nd,
                                float* __restrict__ S) {
  __shared__ __align__(16) unsigned char As[BM * BK * 2];
  __shared__ __align__(16) unsigned char Bs[BN * BK * 2];

  const int b  = blockIdx.z;
  const int mt = blockIdx.y;
  const int nt = blockIdx.x;
  const int tid  = threadIdx.x;
  const int lane = tid & 63;
  const int w    = tid >> 6;
  const int wm   = w >> 1, wn = w & 1;

  const float* Ab = c  + ((size_t)b * T_ + (size_t)mt * BM) * D_;
  const float* Bb = yd + ((size_t)b * N_ + (size_t)nt * BN) * D_;

  f32x4 acc[4][4] = {};

  for (int k0 = 0; k0 < D_; k0 += BK) {
    // ---- stage: 128 rows x 64 cols of f32 each for A and B -> bf16 LDS ----
#pragma unroll
    for (int j = 0; j < 8; ++j) {
      const int g   = j * 256 + tid;   // float4 index within the tile (2048)
      const int row = g >> 4;          // 16 float4s per 64-col row
      const int c4  = g & 15;
      const float4 va = *(const float4*)(Ab + (size_t)row * D_ + k0 + (c4 << 2));
      const float4 vb = *(const float4*)(Bb + (size_t)row * D_ + k0 + (c4 << 2));
      // swizzled byte offset: row*128 + ((col/8)^(row&7))*16 + (col%8)*2
      const int off = (row << 7) + ((((c4 >> 1) ^ (row & 7))) << 4) + ((c4 & 1) << 3);
      uint2 pa, pb;
      pa.x = pack2bf(va.x, va.y); pa.y = pack2bf(va.z, va.w);
      pb.x = pack2bf(vb.x, vb.y); pb.y = pack2bf(vb.z, vb.w);
      *(uint2*)(As + off) = pa;
      *(uint2*)(Bs + off) = pb;
    }
    __syncthreads();

    // ---- compute: 2 k-steps of 32, 16 MFMA each ----
#pragma unroll
    for (int ks = 0; ks < BK / 32; ++ks) {
      bf16x8 af[4], bfr[4];
#pragma unroll
      for (int i = 0; i < 4; ++i) {
        const int ar  = wm * 64 + i * 16 + (lane & 15);
        const int ach = (ks * 4 + (lane >> 4)) ^ (ar & 7);
        af[i] = *(const bf16x8*)(As + (ar << 7) + (ach << 4));
        const int br  = wn * 64 + i * 16 + (lane & 15);
        const int bch = (ks * 4 + (lane >> 4)) ^ (br & 7);
        bfr[i] = *(const bf16x8*)(Bs + (br << 7) + (bch << 4));
      }
#pragma unroll
      for (int mi = 0; mi < 4; ++mi)
#pragma unroll
        for (int ni = 0; ni < 4; ++ni)
          acc[mi][ni] = __builtin_amdgcn_mfma_f32_16x16x32_bf16(
              af[mi], bfr[ni], acc[mi][ni], 0, 0, 0);
    }
    __syncthreads();
  }

  // ---- epilogue: scale -> exp -> row-sum over this 128-col tile ----
  const int tbase = mt * BM + wm * 64;
  const int nbase = nt * BN + wn * 64;
  float invd[4];
#pragma unroll
  for (int ni = 0; ni < 4; ++ni)
    invd[ni] = inv_nd[b * N_ + nbase + ni * 16 + (lane & 15)];

#pragma unroll
  for (int mi = 0; mi < 4; ++mi) {
    const int t0 = tbase + mi * 16 + ((lane >> 4) << 2);
#pragma unroll
    for (int r = 0; r < 4; ++r) {
      const float invc = inv_nc[b * T_ + t0 + r];
      float s = 0.f;
#pragma unroll
      for (int ni = 0; ni < 4; ++ni)
        s += __expf(acc[mi][ni][r] * invc * invd[ni]);
      s += __shfl_xor(s, 1);
      s += __shfl_xor(s, 2);
      s += __shfl_xor(s, 4);
      s += __shfl_xor(s, 8);
      if ((lane & 15) == 0) atomicAdd(&S[b * T_ + t0 + r], s);
    }
  }
}

// ---------------------------------------------------------------------------
// Kernel C: loss = sum_{b,t} log(S + exp(r_t)) - r_t   (atomicAdd into out)
// ---------------------------------------------------------------------------
__global__ void final_loss(const float* __restrict__ S,
                           const float* __restrict__ rt,
                           float* __restrict__ out) {
  const int tid = threadIdx.x;
  float sum = 0.f;
  for (int i = blockIdx.x * blockDim.x + tid; i < B_ * T_;
       i += gridDim.x * blockDim.x) {
    const float r = rt[i];
    sum += logf(S[i] + __expf(r)) - r;
  }
#pragma unroll
  for (int m = 32; m; m >>= 1) sum += __shfl_xor(sum, m);
  __shared__ float ws[4];
  if ((tid & 63) == 0) ws[tid >> 6] = sum;
  __syncthreads();
  if (tid == 0) atomicAdd(out, ws[0] + ws[1] + ws[2] + ws[3]);
}

// ---------------------------------------------------------------------------
extern "C" void kernel_launch(void* const* d_in, const int* in_sizes, int n_in,
                              void* d_out, int out_size, void* d_ws, size_t ws_size,
                              hipStream_t stream) {
  (void)in_sizes; (void)n_in; (void)out_size; (void)ws_size;
  const float* c  = (const float*)d_in[0];
  const float* yt = (const float*)d_in[1];
  const float* yd = (const float*)d_in[2];
  float* out = (float*)d_out;

  float* inv_nc = (float*)d_ws;            // B*T
  float* rt     = inv_nc + B_ * T_;        // B*T
  float* inv_nd = rt + B_ * T_;            // B*N
  float* S      = inv_nd + B_ * N_;        // B*T
  // total ws use: 204800 floats = 800 KiB

  hipMemsetAsync(S, 0, (size_t)B_ * T_ * sizeof(float), stream);
  hipMemsetAsync(out, 0, sizeof(float), stream);

  rownorms_ct<<<B_ * T_ / 4, 256, 0, stream>>>(c, yt, inv_nc, rt);
  rownorms_d<<<B_ * N_ / 4, 256, 0, stream>>>(yd, inv_nd);

  dim3 gB(N_ / BN, T_ / BM, B_);  // (4, 32, 16); x-fastest -> A-tile L2 reuse
  gemm_exp_rowsum<<<gB, 256, 0, stream>>>(c, yd, inv_nc, inv_nd, S);

  final_loss<<<64, 256, 0, stream>>>(S, rt, out);
}

// Round 2
// 157.187 us; speedup vs baseline: 1.3825x; 1.3825x over previous
//
#include <hip/hip_runtime.h>
#include <hip/hip_bf16.h>

// Shapes are fixed by the problem definition.
#define B_   16
#define T_   4096
#define N_   512
#define D_   512
#define EPSF 1e-8f

// GEMM tile params
#define BM 128
#define BN 128
#define BK 64

typedef __attribute__((ext_vector_type(8))) short bf16x8; // 8 bf16 = 4 VGPRs
typedef __attribute__((ext_vector_type(4))) float f32x4;

// round-to-nearest-even f32 -> bf16, packed pair into one u32
__device__ __forceinline__ unsigned int pack2bf(float a, float b) {
  unsigned int ua = __float_as_uint(a);
  ua += 0x7fffu + ((ua >> 16) & 1u);
  unsigned int ub = __float_as_uint(b);
  ub += 0x7fffu + ((ub >> 16) & 1u);
  return (ua >> 16) | (ub & 0xffff0000u);
}

// async global->LDS, 16 B per lane (guide: width=16 is the +67% lever)
__device__ __forceinline__ void gload_lds16(const void* g, void* l) {
  __builtin_amdgcn_global_load_lds(
      (const __attribute__((address_space(1))) unsigned int*)g,
      (__attribute__((address_space(3))) unsigned int*)l, 16, 0, 0);
}

// ---------------------------------------------------------------------------
// Kernel A1: one wave per (b,t) row. ||c||, ||y_t||, dot(c,y_t).
// inv_nc = 1/max(||c||,eps); rt = dot/(n_t*n_c). Optionally writes bf16 c.
// ---------------------------------------------------------------------------
__global__ void rownorms_ct(const float* __restrict__ c,
                            const float* __restrict__ yt,
                            float* __restrict__ inv_nc,
                            float* __restrict__ rt,
                            unsigned short* __restrict__ cbf) {
  const int wave = blockIdx.x * (blockDim.x >> 6) + (threadIdx.x >> 6);
  const int lane = threadIdx.x & 63;
  if (wave >= B_ * T_) return;
  const float4* cp = (const float4*)(c + (size_t)wave * D_);
  const float4* tp = (const float4*)(yt + (size_t)wave * D_);
  float cc = 0.f, tt = 0.f, ct = 0.f;
#pragma unroll
  for (int i = 0; i < D_ / 4 / 64; ++i) {  // 2 iters
    float4 a = cp[lane + 64 * i];
    float4 b = tp[lane + 64 * i];
    cc += a.x * a.x + a.y * a.y + a.z * a.z + a.w * a.w;
    tt += b.x * b.x + b.y * b.y + b.z * b.z + b.w * b.w;
    ct += a.x * b.x + a.y * b.y + a.z * b.z + a.w * b.w;
    if (cbf) {
      uint2 p;
      p.x = pack2bf(a.x, a.y);
      p.y = pack2bf(a.z, a.w);
      *(uint2*)(cbf + (size_t)wave * D_ + ((lane + 64 * i) << 2)) = p;
    }
  }
#pragma unroll
  for (int m = 32; m; m >>= 1) {
    cc += __shfl_xor(cc, m);
    tt += __shfl_xor(tt, m);
    ct += __shfl_xor(ct, m);
  }
  if (lane == 0) {
    float nc = fmaxf(sqrtf(cc), EPSF);
    float nt = fmaxf(sqrtf(tt), EPSF);
    inv_nc[wave] = 1.f / nc;
    rt[wave] = ct / (nt * nc);
  }
}

// ---------------------------------------------------------------------------
// Kernel A2: one wave per (b,n) distractor row -> inv_nd (+ optional bf16).
// ---------------------------------------------------------------------------
__global__ void rownorms_d(const float* __restrict__ yd,
                           float* __restrict__ inv_nd,
                           unsigned short* __restrict__ ydbf) {
  const int wave = blockIdx.x * (blockDim.x >> 6) + (threadIdx.x >> 6);
  const int lane = threadIdx.x & 63;
  if (wave >= B_ * N_) return;
  const float4* dp = (const float4*)(yd + (size_t)wave * D_);
  float dd = 0.f;
#pragma unroll
  for (int i = 0; i < D_ / 4 / 64; ++i) {
    float4 a = dp[lane + 64 * i];
    dd += a.x * a.x + a.y * a.y + a.z * a.z + a.w * a.w;
    if (ydbf) {
      uint2 p;
      p.x = pack2bf(a.x, a.y);
      p.y = pack2bf(a.z, a.w);
      *(uint2*)(ydbf + (size_t)wave * D_ + ((lane + 64 * i) << 2)) = p;
    }
  }
#pragma unroll
  for (int m = 32; m; m >>= 1) dd += __shfl_xor(dd, m);
  if (lane == 0) inv_nd[wave] = 1.f / fmaxf(sqrtf(dd), EPSF);
}

// ---------------------------------------------------------------------------
// Shared epilogue: scale -> exp -> row-sum over the 128-col tile, atomics
// into S[b,t]. C/D layout (verified r1): col=lane&15, row=(lane>>4)*4+reg.
// ---------------------------------------------------------------------------
__device__ __forceinline__ void epilogue_exp_rowsum(
    const f32x4 acc[4][4], const float* __restrict__ inv_nc,
    const float* __restrict__ inv_nd, float* __restrict__ S,
    int b, int mt, int nt, int wm, int wn, int lane) {
  const int tbase = mt * BM + wm * 64;
  const int nbase = nt * BN + wn * 64;
  float invd[4];
#pragma unroll
  for (int ni = 0; ni < 4; ++ni)
    invd[ni] = inv_nd[b * N_ + nbase + ni * 16 + (lane & 15)];
#pragma unroll
  for (int mi = 0; mi < 4; ++mi) {
    const int t0 = tbase + mi * 16 + ((lane >> 4) << 2);
#pragma unroll
    for (int r = 0; r < 4; ++r) {
      const float invc = inv_nc[b * T_ + t0 + r];
      float s = 0.f;
#pragma unroll
      for (int ni = 0; ni < 4; ++ni)
        s += __expf(acc[mi][ni][r] * invc * invd[ni]);
      s += __shfl_xor(s, 1);
      s += __shfl_xor(s, 2);
      s += __shfl_xor(s, 4);
      s += __shfl_xor(s, 8);
      if ((lane & 15) == 0) atomicAdd(&S[b * T_ + t0 + r], s);
    }
  }
}

// ---------------------------------------------------------------------------
// Kernel B (fast path): bf16 inputs, global_load_lds staging.
// LDS layout linear in chunk index; swizzle achieved by pre-swizzling the
// GLOBAL source chunk (m173: linear dest + inv-swz source + swz read).
// LDS[row][ch] = global[row][ch ^ (row&7)]; read k-chunk kc at LDS
// chunk kc ^ (row&7)  (identical read addressing to r1, verified).
// ---------------------------------------------------------------------------
__launch_bounds__(256)
__global__ void gemm_exp_rowsum_bf16(const unsigned short* __restrict__ cbf,
                                     const unsigned short* __restrict__ ydbf,
                                     const float* __restrict__ inv_nc,
                                     const float* __restrict__ inv_nd,
                                     float* __restrict__ S) {
  __shared__ __align__(16) unsigned char As[BM * BK * 2];
  __shared__ __align__(16) unsigned char Bs[BN * BK * 2];

  const int b  = blockIdx.z;
  const int mt = blockIdx.y;
  const int nt = blockIdx.x;
  const int tid  = threadIdx.x;
  const int lane = tid & 63;
  const int w    = tid >> 6;
  const int wm   = w >> 1, wn = w & 1;

  const unsigned short* Ab = cbf  + ((size_t)b * T_ + (size_t)mt * BM) * D_;
  const unsigned short* Bb = ydbf + ((size_t)b * N_ + (size_t)nt * BN) * D_;

  f32x4 acc[4][4] = {};

  for (int k0 = 0; k0 < D_; k0 += BK) {
    // ---- stage: 128 rows x 64 bf16 each = 16 KiB per matrix ----
    // chunk = 16 B = 8 bf16; 8 chunks per row; 1024 chunks per matrix.
#pragma unroll
    for (int j = 0; j < 4; ++j) {
      const int g   = j * 256 + tid;      // linear chunk index 0..1023
      const int row = g >> 3;
      const int sch = (g & 7) ^ (row & 7);  // inverse-swizzled source chunk
      const size_t goff = (size_t)row * D_ + k0 + (sch << 3);
      gload_lds16(Ab + goff, As + (g << 4));
      gload_lds16(Bb + goff, Bs + (g << 4));
    }
    __syncthreads();  // compiler emits vmcnt(0) drain before barrier

    // ---- compute: 2 k-steps of 32, 16 MFMA each ----
#pragma unroll
    for (int ks = 0; ks < BK / 32; ++ks) {
      bf16x8 af[4], bfr[4];
#pragma unroll
      for (int i = 0; i < 4; ++i) {
        const int ar  = wm * 64 + i * 16 + (lane & 15);
        const int ach = (ks * 4 + (lane >> 4)) ^ (ar & 7);
        af[i] = *(const bf16x8*)(As + (ar << 7) + (ach << 4));
        const int br  = wn * 64 + i * 16 + (lane & 15);
        const int bch = (ks * 4 + (lane >> 4)) ^ (br & 7);
        bfr[i] = *(const bf16x8*)(Bs + (br << 7) + (bch << 4));
      }
#pragma unroll
      for (int mi = 0; mi < 4; ++mi)
#pragma unroll
        for (int ni = 0; ni < 4; ++ni)
          acc[mi][ni] = __builtin_amdgcn_mfma_f32_16x16x32_bf16(
              af[mi], bfr[ni], acc[mi][ni], 0, 0, 0);
    }
    __syncthreads();
  }

  epilogue_exp_rowsum(acc, inv_nc, inv_nd, S, b, mt, nt, wm, wn, lane);
}

// ---------------------------------------------------------------------------
// Kernel B (fallback, r1 verbatim): f32 inputs, reg-staged cvt in-loop.
// Used only if ws_size can't hold the bf16 copies.
// ---------------------------------------------------------------------------
__launch_bounds__(256, 2)
__global__ void gemm_exp_rowsum_f32(const float* __restrict__ c,
                                    const float* __restrict__ yd,
                                    const float* __restrict__ inv_nc,
                                    const float* __restrict__ inv_nd,
                                    float* __restrict__ S) {
  __shared__ __align__(16) unsigned char As[BM * BK * 2];
  __shared__ __align__(16) unsigned char Bs[BN * BK * 2];

  const int b  = blockIdx.z;
  const int mt = blockIdx.y;
  const int nt = blockIdx.x;
  const int tid  = threadIdx.x;
  const int lane = tid & 63;
  const int w    = tid >> 6;
  const int wm   = w >> 1, wn = w & 1;

  const float* Ab = c  + ((size_t)b * T_ + (size_t)mt * BM) * D_;
  const float* Bb = yd + ((size_t)b * N_ + (size_t)nt * BN) * D_;

  f32x4 acc[4][4] = {};

  for (int k0 = 0; k0 < D_; k0 += BK) {
#pragma unroll
    for (int j = 0; j < 8; ++j) {
      const int g   = j * 256 + tid;
      const int row = g >> 4;
      const int c4  = g & 15;
      const float4 va = *(const float4*)(Ab + (size_t)row * D_ + k0 + (c4 << 2));
      const float4 vb = *(const float4*)(Bb + (size_t)row * D_ + k0 + (c4 << 2));
      const int off = (row << 7) + ((((c4 >> 1) ^ (row & 7))) << 4) + ((c4 & 1) << 3);
      uint2 pa, pb;
      pa.x = pack2bf(va.x, va.y); pa.y = pack2bf(va.z, va.w);
      pb.x = pack2bf(vb.x, vb.y); pb.y = pack2bf(vb.z, vb.w);
      *(uint2*)(As + off) = pa;
      *(uint2*)(Bs + off) = pb;
    }
    __syncthreads();

#pragma unroll
    for (int ks = 0; ks < BK / 32; ++ks) {
      bf16x8 af[4], bfr[4];
#pragma unroll
      for (int i = 0; i < 4; ++i) {
        const int ar  = wm * 64 + i * 16 + (lane & 15);
        const int ach = (ks * 4 + (lane >> 4)) ^ (ar & 7);
        af[i] = *(const bf16x8*)(As + (ar << 7) + (ach << 4));
        const int br  = wn * 64 + i * 16 + (lane & 15);
        const int bch = (ks * 4 + (lane >> 4)) ^ (br & 7);
        bfr[i] = *(const bf16x8*)(Bs + (br << 7) + (bch << 4));
      }
#pragma unroll
      for (int mi = 0; mi < 4; ++mi)
#pragma unroll
        for (int ni = 0; ni < 4; ++ni)
          acc[mi][ni] = __builtin_amdgcn_mfma_f32_16x16x32_bf16(
              af[mi], bfr[ni], acc[mi][ni], 0, 0, 0);
    }
    __syncthreads();
  }

  epilogue_exp_rowsum(acc, inv_nc, inv_nd, S, b, mt, nt, wm, wn, lane);
}

// ---------------------------------------------------------------------------
// Kernel C: loss = sum_{b,t} log(S + exp(r_t)) - r_t
// ---------------------------------------------------------------------------
__global__ void final_loss(const float* __restrict__ S,
                           const float* __restrict__ rt,
                           float* __restrict__ out) {
  const int tid = threadIdx.x;
  float sum = 0.f;
  for (int i = blockIdx.x * blockDim.x + tid; i < B_ * T_;
       i += gridDim.x * blockDim.x) {
    const float r = rt[i];
    sum += logf(S[i] + __expf(r)) - r;
  }
#pragma unroll
  for (int m = 32; m; m >>= 1) sum += __shfl_xor(sum, m);
  __shared__ float ws[4];
  if ((tid & 63) == 0) ws[tid >> 6] = sum;
  __syncthreads();
  if (tid == 0) atomicAdd(out, ws[0] + ws[1] + ws[2] + ws[3]);
}

// ---------------------------------------------------------------------------
extern "C" void kernel_launch(void* const* d_in, const int* in_sizes, int n_in,
                              void* d_out, int out_size, void* d_ws, size_t ws_size,
                              hipStream_t stream) {
  (void)in_sizes; (void)n_in; (void)out_size;
  const float* c  = (const float*)d_in[0];
  const float* yt = (const float*)d_in[1];
  const float* yd = (const float*)d_in[2];
  float* out = (float*)d_out;

  // ws layout: [cbf: B*T*D u16][ydbf: B*N*D u16][inv_nc][rt][inv_nd][S]
  const size_t cbf_n  = (size_t)B_ * T_ * D_;            // 33.5M u16 = 64 MiB
  const size_t ydbf_n = (size_t)B_ * N_ * D_;            // 4.2M u16 = 8 MiB
  const size_t stats_n = (size_t)B_ * T_ * 3 + B_ * N_;  // floats
  const size_t need = cbf_n * 2 + ydbf_n * 2 + stats_n * 4;
  const bool fast = ws_size >= need;

  unsigned short* cbf  = fast ? (unsigned short*)d_ws : nullptr;
  unsigned short* ydbf = fast ? cbf + cbf_n : nullptr;
  float* stats = fast ? (float*)(ydbf + ydbf_n) : (float*)d_ws;
  float* inv_nc = stats;                 // B*T
  float* rt     = inv_nc + B_ * T_;      // B*T
  float* inv_nd = rt + B_ * T_;          // B*N
  float* S      = inv_nd + B_ * N_;      // B*T

  hipMemsetAsync(S, 0, (size_t)B_ * T_ * sizeof(float), stream);
  hipMemsetAsync(out, 0, sizeof(float), stream);

  rownorms_ct<<<B_ * T_ / 4, 256, 0, stream>>>(c, yt, inv_nc, rt, cbf);
  rownorms_d<<<B_ * N_ / 4, 256, 0, stream>>>(yd, inv_nd, ydbf);

  dim3 gB(N_ / BN, T_ / BM, B_);  // (4, 32, 16); x-fastest -> A-tile L2 reuse
  if (fast)
    gemm_exp_rowsum_bf16<<<gB, 256, 0, stream>>>(cbf, ydbf, inv_nc, inv_nd, S);
  else
    gemm_exp_rowsum_f32<<<gB, 256, 0, stream>>>(c, yd, inv_nc, inv_nd, S);

  final_loss<<<64, 256, 0, stream>>>(S, rt, out);
}

// Round 3
// 155.369 us; speedup vs baseline: 1.3987x; 1.0117x over previous
//
#include <hip/hip_runtime.h>
#include <hip/hip_bf16.h>

// Shapes are fixed by the problem definition.
#define B_   16
#define T_   4096
#define N_   512
#define D_   512
#define EPSF 1e-8f

// GEMM tile params
#define BM 128
#define BN 128
#define BK 64

typedef __attribute__((ext_vector_type(8))) short bf16x8; // 8 bf16 = 4 VGPRs
typedef __attribute__((ext_vector_type(4))) float f32x4;

// round-to-nearest-even f32 -> bf16, packed pair into one u32
__device__ __forceinline__ unsigned int pack2bf(float a, float b) {
  unsigned int ua = __float_as_uint(a);
  ua += 0x7fffu + ((ua >> 16) & 1u);
  unsigned int ub = __float_as_uint(b);
  ub += 0x7fffu + ((ub >> 16) & 1u);
  return (ua >> 16) | (ub & 0xffff0000u);
}

// async global->LDS, 16 B per lane (guide: width=16 is the +67% lever)
__device__ __forceinline__ void gload_lds16(const void* g, void* l) {
  __builtin_amdgcn_global_load_lds(
      (const __attribute__((address_space(1))) unsigned int*)g,
      (__attribute__((address_space(3))) unsigned int*)l, 16, 0, 0);
}

// ---------------------------------------------------------------------------
// Kernel A1: 16 threads per row, 16 rows per block (4 rows/wave).
// Each thread: 8 float4 of c + 8 float4 of yt (32 elems), register partials,
// 4-step shfl_xor reduce within the 16-lane group. Writes bf16 c copy.
// Restructured r3: 1 wave/row had an 18-op serial shuffle chain per 2 KiB
// row -> latency-bound at 2 TB/s. This shape: 12 shuffles per 4 rows.
// ---------------------------------------------------------------------------
__global__ void rownorms_ct(const float* __restrict__ c,
                            const float* __restrict__ yt,
                            float* __restrict__ inv_nc,
                            float* __restrict__ rt,
                            unsigned short* __restrict__ cbf) {
  const int tid = threadIdx.x;
  const int g   = tid >> 4;        // row group within block (0..15)
  const int t   = tid & 15;        // sub-lane within row
  const int row = blockIdx.x * 16 + g;
  const float* cr = c  + (size_t)row * D_;
  const float* tr = yt + (size_t)row * D_;
  unsigned short* ob = cbf + (size_t)row * D_;

  float cc = 0.f, tt = 0.f, ct = 0.f;
#pragma unroll
  for (int k = 0; k < 8; ++k) {
    const int col = k * 64 + t * 4;
    float4 a = *(const float4*)(cr + col);
    float4 b = *(const float4*)(tr + col);
    cc += a.x * a.x + a.y * a.y + a.z * a.z + a.w * a.w;
    tt += b.x * b.x + b.y * b.y + b.z * b.z + b.w * b.w;
    ct += a.x * b.x + a.y * b.y + a.z * b.z + a.w * b.w;
    uint2 p;
    p.x = pack2bf(a.x, a.y);
    p.y = pack2bf(a.z, a.w);
    *(uint2*)(ob + col) = p;
  }
#pragma unroll
  for (int m = 1; m < 16; m <<= 1) {
    cc += __shfl_xor(cc, m);
    tt += __shfl_xor(tt, m);
    ct += __shfl_xor(ct, m);
  }
  if (t == 0) {
    float nc = fmaxf(sqrtf(cc), EPSF);
    float nt = fmaxf(sqrtf(tt), EPSF);
    inv_nc[row] = 1.f / nc;
    rt[row] = ct / (nt * nc);
  }
}

// ---------------------------------------------------------------------------
// Kernel A2: same 16-threads-per-row shape for distractors -> inv_nd + bf16.
// ---------------------------------------------------------------------------
__global__ void rownorms_d(const float* __restrict__ yd,
                           float* __restrict__ inv_nd,
                           unsigned short* __restrict__ ydbf) {
  const int tid = threadIdx.x;
  const int g   = tid >> 4;
  const int t   = tid & 15;
  const int row = blockIdx.x * 16 + g;
  const float* dr = yd + (size_t)row * D_;
  unsigned short* ob = ydbf + (size_t)row * D_;

  float dd = 0.f;
#pragma unroll
  for (int k = 0; k < 8; ++k) {
    const int col = k * 64 + t * 4;
    float4 a = *(const float4*)(dr + col);
    dd += a.x * a.x + a.y * a.y + a.z * a.z + a.w * a.w;
    uint2 p;
    p.x = pack2bf(a.x, a.y);
    p.y = pack2bf(a.z, a.w);
    *(uint2*)(ob + col) = p;
  }
#pragma unroll
  for (int m = 1; m < 16; m <<= 1) dd += __shfl_xor(dd, m);
  if (t == 0) inv_nd[row] = 1.f / fmaxf(sqrtf(dd), EPSF);
}

// ---------------------------------------------------------------------------
// Shared epilogue: scale -> exp -> row-sum over the 128-col tile, atomics
// into S[b,t]. C/D layout (verified r1): col=lane&15, row=(lane>>4)*4+reg.
// ---------------------------------------------------------------------------
__device__ __forceinline__ void epilogue_exp_rowsum(
    const f32x4 acc[4][4], const float* __restrict__ inv_nc,
    const float* __restrict__ inv_nd, float* __restrict__ S,
    int b, int mt, int nt, int wm, int wn, int lane) {
  const int tbase = mt * BM + wm * 64;
  const int nbase = nt * BN + wn * 64;
  float invd[4];
#pragma unroll
  for (int ni = 0; ni < 4; ++ni)
    invd[ni] = inv_nd[b * N_ + nbase + ni * 16 + (lane & 15)];
#pragma unroll
  for (int mi = 0; mi < 4; ++mi) {
    const int t0 = tbase + mi * 16 + ((lane >> 4) << 2);
#pragma unroll
    for (int r = 0; r < 4; ++r) {
      const float invc = inv_nc[b * T_ + t0 + r];
      float s = 0.f;
#pragma unroll
      for (int ni = 0; ni < 4; ++ni)
        s += __expf(acc[mi][ni][r] * invc * invd[ni]);
      s += __shfl_xor(s, 1);
      s += __shfl_xor(s, 2);
      s += __shfl_xor(s, 4);
      s += __shfl_xor(s, 8);
      if ((lane & 15) == 0) atomicAdd(&S[b * T_ + t0 + r], s);
    }
  }
}

// ---------------------------------------------------------------------------
// Kernel B: bf16 inputs, global_load_lds staging (m97 structure).
// LDS layout linear in chunk index; swizzle achieved by pre-swizzling the
// GLOBAL source chunk (m173: linear dest + inv-swz source + swz read).
// LDS[row][ch] = global[row][ch ^ (row&7)]; read k-chunk kc at LDS
// chunk kc ^ (row&7)  (read addressing verified r1, 0 bank conflicts).
// ---------------------------------------------------------------------------
__launch_bounds__(256)
__global__ void gemm_exp_rowsum_bf16(const unsigned short* __restrict__ cbf,
                                     const unsigned short* __restrict__ ydbf,
                                     const float* __restrict__ inv_nc,
                                     const float* __restrict__ inv_nd,
                                     float* __restrict__ S) {
  __shared__ __align__(16) unsigned char As[BM * BK * 2];
  __shared__ __align__(16) unsigned char Bs[BN * BK * 2];

  const int b  = blockIdx.z;
  const int mt = blockIdx.y;
  const int nt = blockIdx.x;
  const int tid  = threadIdx.x;
  const int lane = tid & 63;
  const int w    = tid >> 6;
  const int wm   = w >> 1, wn = w & 1;

  const unsigned short* Ab = cbf  + ((size_t)b * T_ + (size_t)mt * BM) * D_;
  const unsigned short* Bb = ydbf + ((size_t)b * N_ + (size_t)nt * BN) * D_;

  f32x4 acc[4][4] = {};

  for (int k0 = 0; k0 < D_; k0 += BK) {
    // ---- stage: 128 rows x 64 bf16 each = 16 KiB per matrix ----
#pragma unroll
    for (int j = 0; j < 4; ++j) {
      const int g   = j * 256 + tid;      // linear chunk index 0..1023
      const int row = g >> 3;
      const int sch = (g & 7) ^ (row & 7);  // inverse-swizzled source chunk
      const size_t goff = (size_t)row * D_ + k0 + (sch << 3);
      gload_lds16(Ab + goff, As + (g << 4));
      gload_lds16(Bb + goff, Bs + (g << 4));
    }
    __syncthreads();

    // ---- compute: 2 k-steps of 32, 16 MFMA each ----
#pragma unroll
    for (int ks = 0; ks < BK / 32; ++ks) {
      bf16x8 af[4], bfr[4];
#pragma unroll
      for (int i = 0; i < 4; ++i) {
        const int ar  = wm * 64 + i * 16 + (lane & 15);
        const int ach = (ks * 4 + (lane >> 4)) ^ (ar & 7);
        af[i] = *(const bf16x8*)(As + (ar << 7) + (ach << 4));
        const int br  = wn * 64 + i * 16 + (lane & 15);
        const int bch = (ks * 4 + (lane >> 4)) ^ (br & 7);
        bfr[i] = *(const bf16x8*)(Bs + (br << 7) + (bch << 4));
      }
#pragma unroll
      for (int mi = 0; mi < 4; ++mi)
#pragma unroll
        for (int ni = 0; ni < 4; ++ni)
          acc[mi][ni] = __builtin_amdgcn_mfma_f32_16x16x32_bf16(
              af[mi], bfr[ni], acc[mi][ni], 0, 0, 0);
    }
    __syncthreads();
  }

  epilogue_exp_rowsum(acc, inv_nc, inv_nd, S, b, mt, nt, wm, wn, lane);
}

// ---------------------------------------------------------------------------
// Kernel C: loss = sum_{b,t} log(S + exp(r_t)) - r_t
// ---------------------------------------------------------------------------
__global__ void final_loss(const float* __restrict__ S,
                           const float* __restrict__ rt,
                           float* __restrict__ out) {
  const int tid = threadIdx.x;
  float sum = 0.f;
  for (int i = blockIdx.x * blockDim.x + tid; i < B_ * T_;
       i += gridDim.x * blockDim.x) {
    const float r = rt[i];
    sum += logf(S[i] + __expf(r)) - r;
  }
#pragma unroll
  for (int m = 32; m; m >>= 1) sum += __shfl_xor(sum, m);
  __shared__ float ws[4];
  if ((tid & 63) == 0) ws[tid >> 6] = sum;
  __syncthreads();
  if (tid == 0) atomicAdd(out, ws[0] + ws[1] + ws[2] + ws[3]);
}

// ---------------------------------------------------------------------------
extern "C" void kernel_launch(void* const* d_in, const int* in_sizes, int n_in,
                              void* d_out, int out_size, void* d_ws, size_t ws_size,
                              hipStream_t stream) {
  (void)in_sizes; (void)n_in; (void)out_size; (void)ws_size;
  const float* c  = (const float*)d_in[0];
  const float* yt = (const float*)d_in[1];
  const float* yd = (const float*)d_in[2];
  float* out = (float*)d_out;

  // ws layout: [cbf: B*T*D u16][ydbf: B*N*D u16][inv_nc][rt][inv_nd][S]
  const size_t cbf_n  = (size_t)B_ * T_ * D_;            // 33.5M u16 = 64 MiB
  const size_t ydbf_n = (size_t)B_ * N_ * D_;            // 4.2M u16 = 8 MiB
  unsigned short* cbf  = (unsigned short*)d_ws;
  unsigned short* ydbf = cbf + cbf_n;
  float* inv_nc = (float*)(ydbf + ydbf_n);  // B*T
  float* rt     = inv_nc + B_ * T_;         // B*T
  float* inv_nd = rt + B_ * T_;             // B*N
  float* S      = inv_nd + B_ * N_;         // B*T

  hipMemsetAsync(S, 0, (size_t)B_ * T_ * sizeof(float), stream);
  hipMemsetAsync(out, 0, sizeof(float), stream);

  rownorms_ct<<<B_ * T_ / 16, 256, 0, stream>>>(c, yt, inv_nc, rt, cbf);
  rownorms_d<<<B_ * N_ / 16, 256, 0, stream>>>(yd, inv_nd, ydbf);

  dim3 gB(N_ / BN, T_ / BM, B_);  // (4, 32, 16); x-fastest -> A-tile L2 reuse
  gemm_exp_rowsum_bf16<<<gB, 256, 0, stream>>>(cbf, ydbf, inv_nc, inv_nd, S);

  final_loss<<<64, 256, 0, stream>>>(S, rt, out);
}

// Round 4
// 111.162 us; speedup vs baseline: 1.9549x; 1.3977x over previous
//
#include <hip/hip_runtime.h>
#include <hip/hip_bf16.h>

// Shapes are fixed by the problem definition.
#define B_   16
#define T_   4096
#define N_   512
#define D_   512
#define EPSF 1e-8f

typedef __attribute__((ext_vector_type(8))) short bf16x8; // 8 bf16 = 4 VGPRs
typedef __attribute__((ext_vector_type(4))) float f32x4;

// round-to-nearest-even f32 -> bf16, packed pair into one u32
__device__ __forceinline__ unsigned int pack2bf(float a, float b) {
  unsigned int ua = __float_as_uint(a);
  ua += 0x7fffu + ((ua >> 16) & 1u);
  unsigned int ub = __float_as_uint(b);
  ub += 0x7fffu + ((ub >> 16) & 1u);
  return (ua >> 16) | (ub & 0xffff0000u);
}

// async global->LDS, 16 B per lane
__device__ __forceinline__ void gload_lds16(const void* g, void* l) {
  __builtin_amdgcn_global_load_lds(
      (const __attribute__((address_space(1))) unsigned int*)g,
      (__attribute__((address_space(3))) unsigned int*)l, 16, 0, 0);
}

// ---------------------------------------------------------------------------
// Kernel A: distractor rows -> inv_nd (f32 norms) + bf16 copy (ydbf).
// 16 threads/row, 16 rows/block (r3-verified).
// ---------------------------------------------------------------------------
__global__ void rownorms_d(const float* __restrict__ yd,
                           float* __restrict__ inv_nd,
                           unsigned short* __restrict__ ydbf) {
  const int tid = threadIdx.x;
  const int g   = tid >> 4;
  const int t   = tid & 15;
  const int row = blockIdx.x * 16 + g;
  const float* dr = yd + (size_t)row * D_;
  unsigned short* ob = ydbf + (size_t)row * D_;

  float dd = 0.f;
#pragma unroll
  for (int k = 0; k < 8; ++k) {
    const int col = k * 64 + t * 4;
    float4 a = *(const float4*)(dr + col);
    dd += a.x * a.x + a.y * a.y + a.z * a.z + a.w * a.w;
    uint2 p;
    p.x = pack2bf(a.x, a.y);
    p.y = pack2bf(a.z, a.w);
    *(uint2*)(ob + col) = p;
  }
#pragma unroll
  for (int m = 1; m < 16; m <<= 1) dd += __shfl_xor(dd, m);
  if (t == 0) inv_nd[row] = 1.f / fmaxf(sqrtf(dd), EPSF);
}

// ---------------------------------------------------------------------------
// Kernel B (mega-fusion): one block per (mt, b) = 128-row band x full N=512.
// Phase 1: read c-band + yt-band f32 once -> inv_nc (LDS), rt (global).
// Phase 2: K-loop; A staged from L2-warm c f32 with in-reg bf16 pack into
//   swizzled As (r1-verified write formula); B staged via global_load_lds
//   from ydbf with inv-swz source (r2-verified). 8 waves (2x4), acc[4][8].
// Phase 3: exp(acc*invc*invd) row-sum -> atomicAdd S.
// Eliminates the 134 MB cbf write+read stream of r2/r3.
// ---------------------------------------------------------------------------
__launch_bounds__(512, 2)
__global__ void fused_ct(const float* __restrict__ c,
                         const float* __restrict__ yt,
                         const unsigned short* __restrict__ ydbf,
                         const float* __restrict__ inv_nd,
                         float* __restrict__ rt,
                         float* __restrict__ S) {
  __shared__ __align__(16) unsigned char As[128 * 64 * 2];  // 16 KB
  __shared__ __align__(16) unsigned char Bs[512 * 64 * 2];  // 64 KB
  __shared__ float s_invc[128];
  __shared__ float s_invd[512];

  const int mt = blockIdx.x;
  const int b  = blockIdx.y;
  const int tid  = threadIdx.x;
  const int lane = tid & 63;
  const int w    = tid >> 6;
  const int wm   = w >> 2, wn = w & 3;   // 2 x 4 waves over 128 x 512 out

  const float* Ab = c  + ((size_t)b * T_ + (size_t)mt * 128) * D_;
  const float* Tb = yt + ((size_t)b * T_ + (size_t)mt * 128) * D_;
  const unsigned short* Bb = ydbf + (size_t)b * N_ * D_;

  // ---- prefetch Bs for k0=0 (hides ydbf L2/HBM latency under phase 1) ----
#pragma unroll
  for (int j = 0; j < 8; ++j) {
    const int g   = j * 512 + tid;          // chunk 0..4095 (16 B each)
    const int row = g >> 3;                 // 8 chunks per 64-bf16 row
    const int sch = (g & 7) ^ (row & 7);    // inverse-swizzled source chunk
    gload_lds16(Bb + (size_t)row * D_ + (sch << 3), Bs + (g << 4));
  }

  s_invd[tid] = inv_nd[b * N_ + tid];

  // ---- phase 1: stats over the 128-row band (16 thr/row, 4 row-passes) ----
  {
    const int t  = tid & 15;
    const int rg = tid >> 4;                // 32 row-groups
#pragma unroll
    for (int rp = 0; rp < 4; ++rp) {
      const int row = rp * 32 + rg;
      const float* cr = Ab + (size_t)row * D_;
      const float* tr = Tb + (size_t)row * D_;
      float cc = 0.f, tt = 0.f, ct = 0.f;
#pragma unroll
      for (int k = 0; k < 8; ++k) {
        const int col = k * 64 + t * 4;
        float4 a  = *(const float4*)(cr + col);
        float4 bb = *(const float4*)(tr + col);
        cc += a.x * a.x + a.y * a.y + a.z * a.z + a.w * a.w;
        tt += bb.x * bb.x + bb.y * bb.y + bb.z * bb.z + bb.w * bb.w;
        ct += a.x * bb.x + a.y * bb.y + a.z * bb.z + a.w * bb.w;
      }
#pragma unroll
      for (int m = 1; m < 16; m <<= 1) {
        cc += __shfl_xor(cc, m);
        tt += __shfl_xor(tt, m);
        ct += __shfl_xor(ct, m);
      }
      if (t == 0) {
        float nc = fmaxf(sqrtf(cc), EPSF);
        float nt = fmaxf(sqrtf(tt), EPSF);
        s_invc[row] = 1.f / nc;
        rt[b * T_ + mt * 128 + row] = ct / (nt * nc);
      }
    }
  }

  f32x4 acc[4][8] = {};

  // ---- phase 2: K-loop (BK=64, 8 iters) ----
  for (int k0i = 0; k0i < 8; ++k0i) {
    const int k0 = k0i * 64;
    // stage A: 128x64 f32 from L2-warm c -> bf16, swizzled LDS write
#pragma unroll
    for (int j = 0; j < 4; ++j) {
      const int g   = j * 512 + tid;        // float4 0..2047
      const int row = g >> 4;               // 16 float4 per 64-col row
      const int c4  = g & 15;
      const float4 va = *(const float4*)(Ab + (size_t)row * D_ + k0 + (c4 << 2));
      const int off = (row << 7) + ((((c4 >> 1) ^ (row & 7))) << 4) + ((c4 & 1) << 3);
      uint2 pa;
      pa.x = pack2bf(va.x, va.y);
      pa.y = pack2bf(va.z, va.w);
      *(uint2*)(As + off) = pa;
    }
    // stage B for k0>0 (k0=0 prefetched above)
    if (k0i > 0) {
#pragma unroll
      for (int j = 0; j < 8; ++j) {
        const int g   = j * 512 + tid;
        const int row = g >> 3;
        const int sch = (g & 7) ^ (row & 7);
        gload_lds16(Bb + (size_t)row * D_ + k0 + (sch << 3), Bs + (g << 4));
      }
    }
    __syncthreads();

#pragma unroll
    for (int ks = 0; ks < 2; ++ks) {
      bf16x8 af[4], bfr[8];
#pragma unroll
      for (int i = 0; i < 4; ++i) {
        const int ar  = wm * 64 + i * 16 + (lane & 15);
        const int ach = (ks * 4 + (lane >> 4)) ^ (ar & 7);
        af[i] = *(const bf16x8*)(As + (ar << 7) + (ach << 4));
      }
#pragma unroll
      for (int n = 0; n < 8; ++n) {
        const int br  = wn * 128 + n * 16 + (lane & 15);
        const int bch = (ks * 4 + (lane >> 4)) ^ (br & 7);
        bfr[n] = *(const bf16x8*)(Bs + (br << 7) + (bch << 4));
      }
#pragma unroll
      for (int mi = 0; mi < 4; ++mi)
#pragma unroll
        for (int ni = 0; ni < 8; ++ni)
          acc[mi][ni] = __builtin_amdgcn_mfma_f32_16x16x32_bf16(
              af[mi], bfr[ni], acc[mi][ni], 0, 0, 0);
    }
    __syncthreads();
  }

  // ---- phase 3: exp epilogue, row-sum over all 512 cols this block ----
  float invd[8];
#pragma unroll
  for (int ni = 0; ni < 8; ++ni)
    invd[ni] = s_invd[wn * 128 + ni * 16 + (lane & 15)];

#pragma unroll
  for (int mi = 0; mi < 4; ++mi) {
    const int t0l = wm * 64 + mi * 16 + ((lane >> 4) << 2);  // local row
#pragma unroll
    for (int r = 0; r < 4; ++r) {
      const float invc = s_invc[t0l + r];
      float s = 0.f;
#pragma unroll
      for (int ni = 0; ni < 8; ++ni)
        s += __expf(acc[mi][ni][r] * invc * invd[ni]);
      s += __shfl_xor(s, 1);
      s += __shfl_xor(s, 2);
      s += __shfl_xor(s, 4);
      s += __shfl_xor(s, 8);
      if ((lane & 15) == 0)
        atomicAdd(&S[b * T_ + mt * 128 + t0l + r], s);
    }
  }
}

// ---------------------------------------------------------------------------
// Kernel C: loss = sum_{b,t} log(S + exp(r_t)) - r_t
// ---------------------------------------------------------------------------
__global__ void final_loss(const float* __restrict__ S,
                           const float* __restrict__ rt,
                           float* __restrict__ out) {
  const int tid = threadIdx.x;
  float sum = 0.f;
  for (int i = blockIdx.x * blockDim.x + tid; i < B_ * T_;
       i += gridDim.x * blockDim.x) {
    const float r = rt[i];
    sum += logf(S[i] + __expf(r)) - r;
  }
#pragma unroll
  for (int m = 32; m; m >>= 1) sum += __shfl_xor(sum, m);
  __shared__ float ws[4];
  if ((tid & 63) == 0) ws[tid >> 6] = sum;
  __syncthreads();
  if (tid == 0) atomicAdd(out, ws[0] + ws[1] + ws[2] + ws[3]);
}

// ---------------------------------------------------------------------------
extern "C" void kernel_launch(void* const* d_in, const int* in_sizes, int n_in,
                              void* d_out, int out_size, void* d_ws, size_t ws_size,
                              hipStream_t stream) {
  (void)in_sizes; (void)n_in; (void)out_size; (void)ws_size;
  const float* c  = (const float*)d_in[0];
  const float* yt = (const float*)d_in[1];
  const float* yd = (const float*)d_in[2];
  float* out = (float*)d_out;

  // ws layout: [ydbf: B*N*D u16][rt: B*T f][inv_nd: B*N f][S: B*T f]
  const size_t ydbf_n = (size_t)B_ * N_ * D_;   // 4.2M u16 = 8 MiB
  unsigned short* ydbf = (unsigned short*)d_ws;
  float* rt     = (float*)(ydbf + ydbf_n);      // B*T
  float* inv_nd = rt + B_ * T_;                 // B*N
  float* S      = inv_nd + B_ * N_;             // B*T

  hipMemsetAsync(S, 0, (size_t)B_ * T_ * sizeof(float), stream);
  hipMemsetAsync(out, 0, sizeof(float), stream);

  rownorms_d<<<B_ * N_ / 16, 256, 0, stream>>>(yd, inv_nd, ydbf);

  dim3 gF(T_ / 128, B_);   // (32, 16) = 512 blocks, 512 threads
  fused_ct<<<gF, 512, 0, stream>>>(c, yt, ydbf, inv_nd, rt, S);

  final_loss<<<64, 256, 0, stream>>>(S, rt, out);
}